// Round 2
// baseline (311.389 us; speedup 1.0000x reference)
//
#include <hip/hip_runtime.h>

#define NPROJ 180
#define DH 192
#define DW 384
#define VN 96
#define ZPER 8
#define ZCH (VN / ZPER)              // 12 z-chunks
#define TCOLS 65                     // u0l in [2,60] (r7-proven, z-independent)
#define TROWS 19                     // vi in [1,17], +1 -> 18 (bound: |v-vc| < 7.95)
#define TSTG 1280                    // 5*256 staged entries (rows 0..19.7, benign in-detector)
#define PSTRIDE (DH * DW)
#define BSTRIDE (NPROJ * DH * DW)

typedef float v2f __attribute__((ext_vector_type(2)));

// r11: ZPER 4->8 + projection-quarters. w and u are exactly z-independent
// (ez, ex have no z component), so rcp/fu/u0l amortize over 8 voxels instead
// of 4: per-voxel fixed cost (setup ~40 instrs, 1 barrier, 5 ds_writes,
// staging fetch) halves. Grid stays 1728 blocks (6.75/CU) by splitting 180
// projections into 4 quarters of 45. Order-free merge: quarters {0,1} ->
// out, {2,3} -> ws (exactly 2 atomic addends per voxel per buffer), then a
// tiny out+=ws pass. Fallback to 2-half variant if ws too small.
// v-window (ZPER=8, re-derived): v-cv = 1200*z/w exactly; |v-vc| <=
// 1200*3.5/682.8 + 1200*44*16.14/(682.8*698.9) = 7.94 < 8 -> iv0=floor(vc)-9,
// 19 rows, detector rows iv0..iv0+19 in [3,188]. u-window r7-proven,
// unchanged by ZPER. LDS 2x1280x8B + anch = ~21.2 KB -> 7 blocks/CU.
template<int PQ, int NQ>
__global__ __launch_bounds__(256, 6) void cone_bp(
    const float* __restrict__ sino,   // [B, P, H, W]
    const float* __restrict__ mats,   // [P, 3, 4]
    float* __restrict__ out,          // [B, Z, Y, X]
    float* __restrict__ ws)           // same shape, quarters 2,3 (NQ=4 only)
{
    __shared__ v2f tile[2][TSTG];     // 20 KB
    __shared__ int2 anch[PQ];         // anchor table

    const int tid = threadIdx.x;
    // 8x8 per-wave lane map (r7-proven)
    const int x = blockIdx.x * 32 + ((tid & 7) | ((tid >> 6) << 3));
    const int y = blockIdx.y * 8 + ((tid >> 3) & 7);
    const int zc = blockIdx.z % ZCH;
    const int qt = blockIdx.z / ZCH;
    const int pbase = qt * PQ;

    const float xw = (float)x - 47.5f;
    const float yw = (float)y - 47.5f;
    const float zw0 = (float)(zc * ZPER) - 47.5f;

    // block-center world coords (tile anchoring)
    const float xwc = (float)(blockIdx.x * 32) - 32.0f;   // +15.5 - 47.5
    const float ywc = (float)(blockIdx.y * 8) - 44.0f;    // +3.5  - 47.5
    const float zwc = (float)(zc * ZPER) - 44.0f;         // +3.5  - 47.5

    const float4* __restrict__ M = (const float4*)mats;

    // ---- anchor table: one projection per thread, once ----
    if (tid < PQ) {
        int p = pbase + tid;
        float4 a0 = M[p * 3 + 0];
        float4 a1 = M[p * 3 + 1];
        float4 a2 = M[p * 3 + 2];
        float unc = fmaf(a0.x, xwc, fmaf(a0.y, ywc, a0.w));
        float vnc = fmaf(a1.x, xwc, fmaf(a1.y, ywc, fmaf(a1.z, zwc, a1.w)));
        float wc  = fmaf(a2.x, xwc, fmaf(a2.y, ywc, a2.w));
        float rwc = __builtin_amdgcn_rcpf(wc);
        anch[tid] = make_int2((int)floorf(unc * rwc) - 31,
                              (int)floorf(vnc * rwc) - 9);
    }

    // ---- staging map: loop-invariant BYTE offsets within a projection ----
    int VgB[5];
#pragma unroll
    for (int k = 0; k < 5; ++k) {
        int li = tid + 256 * k;
        int row = li / TCOLS;
        int col = li - row * TCOLS;
        VgB[k] = (row * DW + col) * 4;
    }

    __syncthreads();    // anchor table ready

    // ---- preload first projection into registers ----
    int cu, cv;         // anchor of the projection currently in g[]
    {
        int2 a = anch[0];
        cu = __builtin_amdgcn_readfirstlane(a.x);
        cv = __builtin_amdgcn_readfirstlane(a.y);
    }
    v2f g[5];
    {
        const char* p0 = (const char*)(sino + pbase * PSTRIDE + cv * DW + cu);
        const char* p1 = p0 + (size_t)BSTRIDE * 4;
#pragma unroll
        for (int k = 0; k < 5; ++k) {
            g[k].x = *(const float*)(p0 + VgB[k]);
            g[k].y = *(const float*)(p1 + VgB[k]);
        }
    }

    v2f acc[ZPER];
#pragma unroll
    for (int k = 0; k < ZPER; ++k) acc[k] = (v2f)(0.0f);

    auto body = [&](int i, v2f* __restrict__ buf) {
        // ---- stage proj i (in g) into buf ----
#pragma unroll
        for (int k = 0; k < 5; ++k)
            buf[tid + 256 * k] = g[k];
        const float nfu = -(float)cu;        // sampling anchor (this proj)
        const float nfv = -(float)cv;

        // ---- issue p+1 staging loads BEFORE barrier+sampling ----
        if (i + 1 < PQ) {
            int2 a = anch[i + 1];
            cu = __builtin_amdgcn_readfirstlane(a.x);
            cv = __builtin_amdgcn_readfirstlane(a.y);
            const char* p0 = (const char*)(sino
                + (pbase + i + 1) * PSTRIDE + cv * DW + cu);
            const char* p1 = p0 + (size_t)BSTRIDE * 4;
#pragma unroll
            for (int k = 0; k < 5; ++k) {
                g[k].x = *(const float*)(p0 + VgB[k]);
                g[k].y = *(const float*)(p1 + VgB[k]);
            }
        }

        __syncthreads();   // buf staged; safe to read

        // ---- sample projection pbase+i (both batches packed in v2f) ----
        const int p = pbase + i;
        float4 r0 = M[p * 3 + 0];
        float4 r1 = M[p * 3 + 1];
        float4 r2 = M[p * 3 + 2];
        float un  = fmaf(r0.x, xw, fmaf(r0.y, yw, r0.w));
        float vn0 = fmaf(r1.x, xw, fmaf(r1.y, yw, r1.w));
        float w   = fmaf(r2.x, xw, fmaf(r2.y, yw, r2.w));
        float rw  = __builtin_amdgcn_rcpf(w);
        float iw2 = rw * rw;                         // FDK 1/w^2
        float ul  = fmaf(un, rw, nfu);               // tile-local u (z-indep)
        float uf  = floorf(ul);
        float fu  = ul - uf;
        int   u0l = (int)uf;
        float vb  = fmaf(fmaf(r1.z, zw0, vn0), rw, nfv);
        float dv  = r1.z * rw;

        // two k-groups of 4 bound live registers; batching depth per group
        // matches r10's proven schedule
#pragma unroll
        for (int gz = 0; gz < 2; ++gz) {
            int   o[4];
            float fv[4];
#pragma unroll
            for (int j = 0; j < 4; ++j) {
                float v  = fmaf(dv, (float)(4 * gz + j), vb);
                float vf = floorf(v);
                fv[j] = v - vf;
                o[j] = (int)vf * TCOLS + u0l;
            }
            v2f E00[4], E01[4], E10[4], E11[4];
#pragma unroll
            for (int j = 0; j < 4; ++j) {
                E00[j] = buf[o[j]];
                E01[j] = buf[o[j] + 1];
                E10[j] = buf[o[j] + TCOLS];
                E11[j] = buf[o[j] + TCOLS + 1];
            }
#pragma unroll
            for (int j = 0; j < 4; ++j) {
                v2f F0 = E00[j] + (E10[j] - E00[j]) * fv[j];
                v2f F1 = E01[j] + (E11[j] - E01[j]) * fv[j];
                v2f H  = F0 + (F1 - F0) * fu;
                acc[4 * gz + j] += H * iw2;
            }
        }
    };

    // unrolled-by-2 so the buffer parity is a compile-time imm offset
    for (int i = 0; i < PQ; i += 2) {
        body(i, tile[0]);
        if (i + 1 < PQ) body(i + 1, tile[1]);
    }

    // ---- merge: exactly 2 atomic addends per voxel per buffer ----
    float* __restrict__ dst = (NQ == 4 && qt >= 2) ? ws : out;
    const int zbase = zc * ZPER;
#pragma unroll
    for (int k = 0; k < ZPER; ++k) {
        unsafeAtomicAdd(&dst[(((size_t)(zbase + k)) * VN + y) * VN + x],
                        acc[k].x);
        unsafeAtomicAdd(&dst[(((size_t)(VN + zbase + k)) * VN + y) * VN + x],
                        acc[k].y);
    }
}

// out += ws, float4-vectorized (2*96^3 floats = 442368 float4)
__global__ __launch_bounds__(256) void add_ws(
    float4* __restrict__ out, const float4* __restrict__ ws, int n4)
{
    int i = blockIdx.x * 256 + threadIdx.x;
    if (i < n4) {
        float4 a = ws[i];
        float4 b = out[i];
        b.x += a.x; b.y += a.y; b.z += a.z; b.w += a.w;
        out[i] = b;
    }
}

extern "C" void kernel_launch(void* const* d_in, const int* in_sizes, int n_in,
                              void* d_out, int out_size, void* d_ws, size_t ws_size,
                              hipStream_t stream) {
    const float* sino = (const float*)d_in[0];   // [2,180,192,384,1] fp32
    const float* mats = (const float*)d_in[1];   // [180,3,4] fp32
    float* out = (float*)d_out;                  // [2,96,96,96,1] fp32
    float* wsf = (float*)d_ws;

    const size_t nvox = (size_t)2 * VN * VN * VN;           // 1769472
    // d_out is poisoned before every launch; atomic merge needs zeros
    hipMemsetAsync(out, 0, (size_t)out_size * sizeof(float), stream);

    if (ws_size >= nvox * sizeof(float)) {
        // 4 projection-quarters: grid 3 x 12 x (12 z-chunks * 4 quarters)
        hipMemsetAsync(wsf, 0, nvox * sizeof(float), stream);
        dim3 grid(VN / 32, VN / 8, ZCH * 4), block(256);
        hipLaunchKernelGGL((cone_bp<NPROJ / 4, 4>), grid, block, 0, stream,
                           sino, mats, out, wsf);
        int n4 = (int)(nvox / 4);
        hipLaunchKernelGGL(add_ws, dim3((n4 + 255) / 256), block, 0, stream,
                           (float4*)out, (const float4*)wsf, n4);
    } else {
        // fallback: 2 halves, same ZPER=8 kernel, no workspace
        dim3 grid(VN / 32, VN / 8, ZCH * 2), block(256);
        hipLaunchKernelGGL((cone_bp<NPROJ / 2, 2>), grid, block, 0, stream,
                           sino, mats, out, (float*)nullptr);
    }
}